// Round 9
// baseline (347.885 us; speedup 1.0000x reference)
//
#include <hip/hip_runtime.h>
#include <hip/hip_bf16.h>

#define NODES 50000
#define EDGES 800000
#define CH 128
#define KTOT 256           // concat K: [x_r (128) | x_c (128)]
#define EB 128             // edges per block

typedef __attribute__((ext_vector_type(8))) __bf16 bf16x8;
typedef __attribute__((ext_vector_type(4))) float f32x4;
typedef unsigned long long u64;

static __device__ __forceinline__ unsigned short f2bf(float f) {
    union { float f; unsigned u; } v; v.f = f;
    unsigned r = v.u + 0x7FFFu + ((v.u >> 16) & 1u);   // RNE
    return (unsigned short)(r >> 16);
}

// ---- phase 0a: x fp32 -> bf16 [50000][128] (exact, no pad) ----
__global__ void k_cvt_x(const float* __restrict__ x, unsigned short* __restrict__ xb) {
    int i = blockIdx.x * blockDim.x + threadIdx.x;      // 6250*256 == NODES*CH/4 exactly
    int base = i << 2;
    const f32x4 v = *reinterpret_cast<const f32x4*>(x + base);
    unsigned short s0 = f2bf(v[0]), s1 = f2bf(v[1]), s2 = f2bf(v[2]), s3 = f2bf(v[3]);
    u64 p = (u64)s0 | ((u64)s1 << 16) | ((u64)s2 << 32) | ((u64)s3 << 48);
    *reinterpret_cast<u64*>(xb + base) = p;
}

// ---- phase 0b: Wb2[256 outcols][256 k] bf16; oc<128 = w_mean row, else w_var row.
// k-layout matches concat: k<128 multiplies x_r, k>=128 multiplies x_c (== torch cat order).
__global__ void k_pack_w2(const float* __restrict__ wm, const float* __restrict__ wv,
                          unsigned short* __restrict__ wb2) {
    int i = blockIdx.x * blockDim.x + threadIdx.x;      // 0..65535
    int oc = i >> 8, k = i & 255;
    const float* w = (oc < 128) ? wm : wv;
    wb2[i] = f2bf(w[(size_t)(oc & 127) * 256 + k]);
}

// ---- fused edge-GEMM: per block, 128 edges.
// LDS A[128 rows][256 k] bf16, 16B granules XOR-swizzled: phys = q ^ (row&7).
// C[oc][edge] = sum_k Wb2[oc][k] * A[edge][k]; write fp32 coalesced (f32x4 per lane).
__global__ __launch_bounds__(256, 2) void k_fused(const int* __restrict__ ei,
                                                  const unsigned short* __restrict__ xb,
                                                  const unsigned short* __restrict__ wb2,
                                                  float* __restrict__ out) {
    __shared__ __align__(16) unsigned short sA[EB * KTOT];   // 64 KB
    const int tid = threadIdx.x;
    const int e0 = blockIdx.x * EB;

    // ---- stage: 4096 granules of 16B; thread t handles granules t, t+256, ...
#pragma unroll
    for (int t = 0; t < 16; ++t) {
        int G = t * 256 + tid;          // granule id
        int row = G >> 5;               // edge row 0..127
        int p = G & 31;                 // physical granule in row
        int q = p ^ (row & 7);          // logical concat-granule (XOR swizzle, bits 0-2)
        int node = (q < 16) ? ei[e0 + row] : ei[EDGES + e0 + row];
        const f32x4 v = *reinterpret_cast<const f32x4*>(xb + (size_t)node * CH + (q & 15) * 8);
        *reinterpret_cast<f32x4*>(sA + (size_t)G * 8) = v;
    }
    __syncthreads();

    const int lane = tid & 63;
    const int wave = tid >> 6;
    const int m0 = (wave >> 1) * 128;   // 0 = mean outcols, 128 = var outcols
    const int n0 = (wave & 1) * 64;     // edge sub-tile base
    const int lr = lane & 15;
    const int kg = lane >> 4;           // 0..3

    f32x4 acc[8][4] = {};
#pragma unroll
    for (int ks = 0; ks < 8; ++ks) {
        bf16x8 af[8], bfr[4];
#pragma unroll
        for (int a = 0; a < 8; ++a)     // A-operand: Wb2 rows (outcols), L2-resident
            af[a] = *reinterpret_cast<const bf16x8*>(
                wb2 + (size_t)(m0 + a * 16 + lr) * KTOT + ks * 32 + kg * 8);
#pragma unroll
        for (int b = 0; b < 4; ++b) {   // B-operand: edge rows from swizzled LDS
            int row = n0 + b * 16 + lr;
            int pb = (ks * 4 + kg) ^ (row & 7);
            bfr[b] = *reinterpret_cast<const bf16x8*>(sA + row * KTOT + pb * 8);
        }
#pragma unroll
        for (int a = 0; a < 8; ++a)
#pragma unroll
            for (int b = 0; b < 4; ++b)
                acc[a][b] = __builtin_amdgcn_mfma_f32_16x16x32_bf16(af[a], bfr[b], acc[a][b], 0, 0, 0);
    }

    // C/D layout [m89]: col = lane&15 (edge), row = (lane>>4)*4 + reg (outcol)
    // -> per lane, one f32x4 = 4 consecutive outcols of one edge: coalesced 16B store.
    const int crow = (lane >> 4) * 4;
    const int ccol = lane & 15;
    float* obase = out + (m0 ? ((size_t)EDGES * CH) : 0);
#pragma unroll
    for (int a = 0; a < 8; ++a) {
        const int oc = (a * 16 + crow);              // 0..124 within the 128-col half
#pragma unroll
        for (int b = 0; b < 4; ++b) {
            const size_t edge = (size_t)(e0 + n0 + b * 16 + ccol);
            __builtin_nontemporal_store(acc[a][b],
                reinterpret_cast<f32x4*>(obase + edge * CH + oc));
        }
    }
}

// ---- last-resort fallback: direct fp32 per-edge GEMV ----
__global__ void k_naive(const float* __restrict__ x, const int* __restrict__ ei,
                        const float* __restrict__ wm, const float* __restrict__ wv,
                        float* __restrict__ out) {
    __shared__ float xs[256];
    int e = blockIdx.x;
    int t = threadIdx.x;
    int r = ei[e], c = ei[EDGES + e];
    xs[t] = (t < 128) ? x[(size_t)r * 128 + t] : x[(size_t)c * 128 + (t - 128)];
    __syncthreads();
    const float* w = (t < 128) ? (wm + (size_t)t * 256) : (wv + (size_t)(t - 128) * 256);
    float acc = 0.f;
#pragma unroll 8
    for (int k = 0; k < 256; ++k) acc = fmaf(xs[k], w[k], acc);
    size_t ooff = (t < 128) ? ((size_t)e * 128 + t)
                            : ((size_t)EDGES * 128 + (size_t)e * 128 + (t - 128));
    out[ooff] = acc;
}

extern "C" void kernel_launch(void* const* d_in, const int* in_sizes, int n_in,
                              void* d_out, int out_size, void* d_ws, size_t ws_size,
                              hipStream_t stream) {
    const float* x  = (const float*)d_in[0];
    const int*   ei = (const int*)d_in[1];
    const float* wm = (const float*)d_in[2];
    const float* wv = (const float*)d_in[3];
    float* out = (float*)d_out;

    const size_t xb_b = (size_t)NODES * CH * 2;     // 12,800,000
    const size_t wb_b = (size_t)KTOT * KTOT * 2;    //    131,072

    if (ws_size < xb_b + wb_b) {          // correctness insurance only
        k_naive<<<EDGES, 256, 0, stream>>>(x, ei, wm, wv, out);
        return;
    }

    unsigned short* xb  = (unsigned short*)d_ws;
    unsigned short* wb2 = (unsigned short*)((char*)d_ws + xb_b);

    k_cvt_x<<<NODES * CH / 4 / 256, 256, 0, stream>>>(x, xb);       // 6250 blocks
    k_pack_w2<<<KTOT * KTOT / 256, 256, 0, stream>>>(wm, wv, wb2);  // 256 blocks
    k_fused<<<EDGES / EB, 256, 0, stream>>>(ei, xb, wb2, out);      // 6250 blocks
}

// Round 10
// 310.258 us; speedup vs baseline: 1.1213x; 1.1213x over previous
//
#include <hip/hip_runtime.h>
#include <hip/hip_bf16.h>

#define NODES 50000
#define EDGES 800000
#define CH 128
#define KTOT 256           // concat K: [x_r (128) | x_c (128)]
#define EB 128             // edges per block

typedef __attribute__((ext_vector_type(8))) __bf16 bf16x8;
typedef __attribute__((ext_vector_type(4))) float f32x4;
typedef unsigned long long u64;

static __device__ __forceinline__ unsigned short f2bf(float f) {
    union { float f; unsigned u; } v; v.f = f;
    unsigned r = v.u + 0x7FFFu + ((v.u >> 16) & 1u);   // RNE
    return (unsigned short)(r >> 16);
}

// ---- phase 0a: x fp32 -> bf16 [50000][128] (exact, no pad) ----
__global__ void k_cvt_x(const float* __restrict__ x, unsigned short* __restrict__ xb) {
    int i = blockIdx.x * blockDim.x + threadIdx.x;      // 6250*256 == NODES*CH/4 exactly
    int base = i << 2;
    const f32x4 v = *reinterpret_cast<const f32x4*>(x + base);
    unsigned short s0 = f2bf(v[0]), s1 = f2bf(v[1]), s2 = f2bf(v[2]), s3 = f2bf(v[3]);
    u64 p = (u64)s0 | ((u64)s1 << 16) | ((u64)s2 << 32) | ((u64)s3 << 48);
    *reinterpret_cast<u64*>(xb + base) = p;
}

// ---- phase 0b: Wb2[256 outcols][256 k] bf16; oc<128 = w_mean row, else w_var row ----
__global__ void k_pack_w2(const float* __restrict__ wm, const float* __restrict__ wv,
                          unsigned short* __restrict__ wb2) {
    int i = blockIdx.x * blockDim.x + threadIdx.x;      // 0..65535
    int oc = i >> 8, k = i & 255;
    const float* w = (oc < 128) ? wm : wv;
    wb2[i] = f2bf(w[(size_t)(oc & 127) * 256 + k]);
}

// ---- fused edge-GEMM, LDS C-transpose for coalesced output ----
// Per block: 128 edges. A[128][256] bf16 in LDS (XOR-swizzled 16B granules).
// MFMA: C[oc][edge] = Wb2 · A^T. Then C staged through LDS (reusing A's buffer)
// and written as two 64 KB linear contiguous NT streams (mean, var).
__global__ __launch_bounds__(256, 2) void k_fused(const int* __restrict__ ei,
                                                  const unsigned short* __restrict__ xb,
                                                  const unsigned short* __restrict__ wb2,
                                                  float* __restrict__ out) {
    __shared__ __align__(16) unsigned char smem[EB * KTOT * 2];   // 64 KB
    unsigned short* sA = (unsigned short*)smem;                   // bf16 A tile
    char* sC = (char*)smem;                                       // fp32 C half (reuse)
    const int tid = threadIdx.x;
    const int e0 = blockIdx.x * EB;

    // ---- stage A: 4096 granules of 16B; phys granule p = q ^ (row&7) ----
#pragma unroll
    for (int t = 0; t < 16; ++t) {
        int G = t * 256 + tid;
        int row = G >> 5;               // edge row 0..127
        int p = G & 31;
        int q = p ^ (row & 7);          // logical concat-granule
        int node = (q < 16) ? ei[e0 + row] : ei[EDGES + e0 + row];
        const f32x4 v = *reinterpret_cast<const f32x4*>(xb + (size_t)node * CH + (q & 15) * 8);
        *reinterpret_cast<f32x4*>(sA + (size_t)G * 8) = v;
    }
    __syncthreads();

    const int lane = tid & 63;
    const int wave = tid >> 6;
    const int half = wave >> 1;         // 0 = mean outcols, 1 = var outcols
    const int m0 = half * 128;
    const int n0 = (wave & 1) * 64;     // edge sub-tile base
    const int lr = lane & 15;
    const int kg = lane >> 4;           // 0..3

    f32x4 acc[8][4] = {};
#pragma unroll
    for (int ks = 0; ks < 8; ++ks) {
        bf16x8 af[8], bfr[4];
#pragma unroll
        for (int a = 0; a < 8; ++a)     // A-operand: Wb2 rows (outcols), L2-resident
            af[a] = *reinterpret_cast<const bf16x8*>(
                wb2 + (size_t)(m0 + a * 16 + lr) * KTOT + ks * 32 + kg * 8);
#pragma unroll
        for (int b = 0; b < 4; ++b) {   // B-operand: edge rows from swizzled LDS
            int row = n0 + b * 16 + lr;
            int pb = (ks * 4 + kg) ^ (row & 7);
            bfr[b] = *reinterpret_cast<const bf16x8*>(sA + row * KTOT + pb * 8);
        }
#pragma unroll
        for (int a = 0; a < 8; ++a)
#pragma unroll
            for (int b = 0; b < 4; ++b)
                acc[a][b] = __builtin_amdgcn_mfma_f32_16x16x32_bf16(af[a], bfr[b], acc[a][b], 0, 0, 0);
    }
    __syncthreads();                     // sA dead after this; reuse as sC

    // C/D layout [m89]: col = lane&15 (edge), row = (lane>>4)*4 + reg (outcol)
    const int crow = (lane >> 4) * 4;
    const int ccol = lane & 15;

#pragma unroll
    for (int ph = 0; ph < 2; ++ph) {     // ph 0 = mean half, ph 1 = var half
        if (half == ph) {
            // dump acc -> sC[edge][oc] fp32, byte-XOR swizzle within each 512B row
#pragma unroll
            for (int a = 0; a < 8; ++a) {
#pragma unroll
                for (int b = 0; b < 4; ++b) {
                    int edge = n0 + b * 16 + ccol;
                    int ocb = (a * 16 + crow) * 4;               // 16B-aligned byte off
                    int phys = ocb ^ ((edge & 7) << 4);
                    *reinterpret_cast<f32x4*>(sC + edge * 512 + phys) = acc[a][b];
                }
            }
        }
        __syncthreads();
        // cooperative copy-out: 64 KB linear contiguous (this block's region)
        char* obase = (char*)(out + (size_t)ph * ((size_t)EDGES * CH) + (size_t)e0 * CH);
#pragma unroll
        for (int t = 0; t < 16; ++t) {
            int flat = t * 4096 + tid * 16;                      // 0..65520
            int edge = flat >> 9;
            int rowoff = flat & 511;
            int phys = rowoff ^ ((edge & 7) << 4);
            f32x4 v = *reinterpret_cast<const f32x4*>(sC + edge * 512 + phys);
            __builtin_nontemporal_store(v, reinterpret_cast<f32x4*>(obase + flat));
        }
        __syncthreads();                 // before next phase reuses sC
    }
}

// ---- last-resort fallback: direct fp32 per-edge GEMV ----
__global__ void k_naive(const float* __restrict__ x, const int* __restrict__ ei,
                        const float* __restrict__ wm, const float* __restrict__ wv,
                        float* __restrict__ out) {
    __shared__ float xs[256];
    int e = blockIdx.x;
    int t = threadIdx.x;
    int r = ei[e], c = ei[EDGES + e];
    xs[t] = (t < 128) ? x[(size_t)r * 128 + t] : x[(size_t)c * 128 + (t - 128)];
    __syncthreads();
    const float* w = (t < 128) ? (wm + (size_t)t * 256) : (wv + (size_t)(t - 128) * 256);
    float acc = 0.f;
#pragma unroll 8
    for (int k = 0; k < 256; ++k) acc = fmaf(xs[k], w[k], acc);
    size_t ooff = (t < 128) ? ((size_t)e * 128 + t)
                            : ((size_t)EDGES * 128 + (size_t)e * 128 + (t - 128));
    out[ooff] = acc;
}

extern "C" void kernel_launch(void* const* d_in, const int* in_sizes, int n_in,
                              void* d_out, int out_size, void* d_ws, size_t ws_size,
                              hipStream_t stream) {
    const float* x  = (const float*)d_in[0];
    const int*   ei = (const int*)d_in[1];
    const float* wm = (const float*)d_in[2];
    const float* wv = (const float*)d_in[3];
    float* out = (float*)d_out;

    const size_t xb_b = (size_t)NODES * CH * 2;     // 12,800,000
    const size_t wb_b = (size_t)KTOT * KTOT * 2;    //    131,072

    if (ws_size < xb_b + wb_b) {          // correctness insurance only
        k_naive<<<EDGES, 256, 0, stream>>>(x, ei, wm, wv, out);
        return;
    }

    unsigned short* xb  = (unsigned short*)d_ws;
    unsigned short* wb2 = (unsigned short*)((char*)d_ws + xb_b);

    k_cvt_x<<<NODES * CH / 4 / 256, 256, 0, stream>>>(x, xb);       // 6250 blocks
    k_pack_w2<<<KTOT * KTOT / 256, 256, 0, stream>>>(wm, wv, wb2);  // 256 blocks
    k_fused<<<EDGES / EB, 256, 0, stream>>>(ei, xb, wb2, out);      // 6250 blocks
}

// Round 11
// 267.155 us; speedup vs baseline: 1.3022x; 1.1613x over previous
//
#include <hip/hip_runtime.h>
#include <hip/hip_bf16.h>

#define NODES 50000
#define EDGES 800000
#define CH 128
#define NCOL 512           // table cols per node: [ym1 | ym2 | yv1 | yv2]
#define MPAD 50048         // 391 * 128
#define EPW 4              // edge-PAIRS per wave per pass (8 edges/wave)

typedef __attribute__((ext_vector_type(8))) __bf16 bf16x8;
typedef __attribute__((ext_vector_type(4))) float f32x4;
typedef unsigned long long u64;

static __device__ __forceinline__ unsigned short f2bf(float f) {
    union { float f; unsigned u; } v; v.f = f;
    unsigned r = v.u + 0x7FFFu + ((v.u >> 16) & 1u);   // RNE
    return (unsigned short)(r >> 16);
}
static __device__ __forceinline__ float bf2f(unsigned short h) {
    union { unsigned u; float f; } v; v.u = ((unsigned)h) << 16;
    return v.f;
}

// ---- phase 0a: x fp32 -> bf16, padded to MPAD rows (pad rows = 0) ----
__global__ void k_cvt_x(const float* __restrict__ x, unsigned short* __restrict__ xb) {
    int i = blockIdx.x * blockDim.x + threadIdx.x;
    if (i >= MPAD * CH / 4) return;
    int base = i << 2;
    unsigned short s0 = 0, s1 = 0, s2 = 0, s3 = 0;
    if (base < NODES * CH) {
        const f32x4 v = *reinterpret_cast<const f32x4*>(x + base);
        s0 = f2bf(v[0]); s1 = f2bf(v[1]); s2 = f2bf(v[2]); s3 = f2bf(v[3]);
    }
    u64 p = (u64)s0 | ((u64)s1 << 16) | ((u64)s2 << 32) | ((u64)s3 << 48);
    *reinterpret_cast<u64*>(xb + base) = p;
}

// ---- phase 0b: Wb[512][128] bf16 (B^T). col n: ym1 | ym2 | yv1 | yv2 ----
__global__ void k_pack_w(const float* __restrict__ wm, const float* __restrict__ wv,
                         unsigned short* __restrict__ wb) {
    int i = blockIdx.x * blockDim.x + threadIdx.x;      // 0..65535
    if (i >= NCOL * CH) return;
    int n = i >> 7, k = i & 127;
    float v;
    if (n < 128)      v = wm[n * 256 + k];               // ym1 = w_mean[:, :128]
    else if (n < 256) v = wm[(n - 128) * 256 + 128 + k]; // ym2 = w_mean[:, 128:]
    else if (n < 384) v = wv[(n - 256) * 256 + k];       // yv1
    else              v = wv[(n - 384) * 256 + 128 + k]; // yv2
    wb[i] = f2bf(v);
}

// ---- phase 1: tab[MPAD][512](bf16) = Xb @ Wb^T (MFMA 16x16x32) ----
__global__ __launch_bounds__(256) void k_gemm(const unsigned short* __restrict__ xb,
                                              const unsigned short* __restrict__ wb,
                                              unsigned short* __restrict__ th) {
    const int lane = threadIdx.x & 63;
    const int wave = threadIdx.x >> 6;
    const int rowbase = blockIdx.x * 128 + (wave >> 1) * 64;
    const int colbase = blockIdx.y * 128 + (wave & 1) * 64;
    const int lr = lane & 15;
    const int kg = lane >> 4;
    f32x4 acc[4][4] = {};
#pragma unroll
    for (int ks = 0; ks < 4; ++ks) {
        const int k = ks * 32 + kg * 8;
        bf16x8 af[4], bfr[4];
#pragma unroll
        for (int a = 0; a < 4; ++a)
            af[a] = *reinterpret_cast<const bf16x8*>(xb + (size_t)(rowbase + a * 16 + lr) * CH + k);
#pragma unroll
        for (int b = 0; b < 4; ++b)
            bfr[b] = *reinterpret_cast<const bf16x8*>(wb + (size_t)(colbase + b * 16 + lr) * CH + k);
#pragma unroll
        for (int a = 0; a < 4; ++a)
#pragma unroll
            for (int b = 0; b < 4; ++b)
                acc[a][b] = __builtin_amdgcn_mfma_f32_16x16x32_bf16(af[a], bfr[b], acc[a][b], 0, 0, 0);
    }
    const int crow = (lane >> 4) * 4;   // C/D: col = lane&15, row = (lane>>4)*4 + reg
    const int ccol = lane & 15;
#pragma unroll
    for (int a = 0; a < 4; ++a)
#pragma unroll
        for (int b = 0; b < 4; ++b)
#pragma unroll
            for (int j = 0; j < 4; ++j) {
                int row = rowbase + a * 16 + crow + j;
                int col = colbase + b * 16 + ccol;
                th[(size_t)row * NCOL + col] = f2bf(acc[a][b][j]);
            }
}

// ---- phase 2: per-HALF pass (0 = mean, 1 = var). 2 edges per wave iter.
// Per pass, table working set = 25.6 MB (cols HALF*256 .. HALF*256+255) -> L3-resident.
// lane: es = lane>>5 selects edge of the pair, j = lane&31 covers 128 cols as f32x4.
template <int HALF>
__global__ __launch_bounds__(256) void k_edges_p(const int* __restrict__ ei,
                                                 const unsigned short* __restrict__ th,
                                                 float* __restrict__ out) {
    const int wave = threadIdx.x >> 6;
    const int lane = threadIdx.x & 63;
    const int es = lane >> 5;
    const int j = lane & 31;
    const int ebase = (blockIdx.x * 4 + wave) * (2 * EPW);

    int rr[EPW], cc[EPW];
#pragma unroll
    for (int i = 0; i < EPW; ++i) {
        int e = ebase + 2 * i + es;
        rr[i] = ei[e];
        cc[i] = ei[EDGES + e];
    }
    u64 pa[EPW], pb[EPW];
#pragma unroll
    for (int i = 0; i < EPW; ++i) {
        pa[i] = *reinterpret_cast<const u64*>(th + (size_t)rr[i] * NCOL + HALF * 256 + j * 4);
        pb[i] = *reinterpret_cast<const u64*>(th + (size_t)cc[i] * NCOL + HALF * 256 + 128 + j * 4);
    }
    const size_t obase = (size_t)HALF * ((size_t)EDGES * 128) + (size_t)j * 4;
#pragma unroll
    for (int i = 0; i < EPW; ++i) {
        const int e = ebase + 2 * i + es;
        f32x4 s;
        s[0] = bf2f((unsigned short)pa[i])         + bf2f((unsigned short)pb[i]);
        s[1] = bf2f((unsigned short)(pa[i] >> 16)) + bf2f((unsigned short)(pb[i] >> 16));
        s[2] = bf2f((unsigned short)(pa[i] >> 32)) + bf2f((unsigned short)(pb[i] >> 32));
        s[3] = bf2f((unsigned short)(pa[i] >> 48)) + bf2f((unsigned short)(pb[i] >> 48));
        __builtin_nontemporal_store(
            s, reinterpret_cast<f32x4*>(out + obase + (size_t)e * 128));
    }
}

// ---- last-resort fallback: direct fp32 per-edge GEMV ----
__global__ void k_naive(const float* __restrict__ x, const int* __restrict__ ei,
                        const float* __restrict__ wm, const float* __restrict__ wv,
                        float* __restrict__ out) {
    __shared__ float xs[256];
    int e = blockIdx.x;
    int t = threadIdx.x;
    int r = ei[e], c = ei[EDGES + e];
    xs[t] = (t < 128) ? x[(size_t)r * 128 + t] : x[(size_t)c * 128 + (t - 128)];
    __syncthreads();
    const float* w = (t < 128) ? (wm + (size_t)t * 256) : (wv + (size_t)(t - 128) * 256);
    float acc = 0.f;
#pragma unroll 8
    for (int k = 0; k < 256; ++k) acc = fmaf(xs[k], w[k], acc);
    size_t ooff = (t < 128) ? ((size_t)e * 128 + t)
                            : ((size_t)EDGES * 128 + (size_t)e * 128 + (t - 128));
    out[ooff] = acc;
}

extern "C" void kernel_launch(void* const* d_in, const int* in_sizes, int n_in,
                              void* d_out, int out_size, void* d_ws, size_t ws_size,
                              hipStream_t stream) {
    const float* x  = (const float*)d_in[0];
    const int*   ei = (const int*)d_in[1];
    const float* wm = (const float*)d_in[2];
    const float* wv = (const float*)d_in[3];
    float* out = (float*)d_out;

    const size_t xb_b = (size_t)MPAD * CH * 2;     // 12,812,288
    const size_t wb_b = (size_t)NCOL * CH * 2;     //    131,072
    const size_t th_b = (size_t)MPAD * NCOL * 2;   // 51,249,152

    if (ws_size < xb_b + wb_b + th_b) {            // correctness insurance only
        k_naive<<<EDGES, 256, 0, stream>>>(x, ei, wm, wv, out);
        return;
    }

    unsigned short* xb  = (unsigned short*)d_ws;
    unsigned short* wb  = (unsigned short*)((char*)d_ws + xb_b);
    unsigned short* tab = (unsigned short*)((char*)d_ws + xb_b + wb_b);

    k_cvt_x<<<(MPAD * CH / 4 + 255) / 256, 256, 0, stream>>>(x, xb);
    k_pack_w<<<(NCOL * CH + 255) / 256, 256, 0, stream>>>(wm, wv, wb);
    dim3 g(MPAD / 128, NCOL / 128);
    k_gemm<<<g, 256, 0, stream>>>(xb, wb, tab);

    const int eb = EDGES / (4 * 2 * EPW);          // 25000 blocks per pass
    k_edges_p<0><<<eb, 256, 0, stream>>>(ei, tab, out);
    k_edges_p<1><<<eb, 256, 0, stream>>>(ei, tab, out);
}

// Round 12
// 226.821 us; speedup vs baseline: 1.5337x; 1.1778x over previous
//
#include <hip/hip_runtime.h>
#include <hip/hip_bf16.h>

#define NODES 50000
#define EDGES 800000
#define CH 128
#define NCOL 512           // table cols per node: [ym1 | ym2 | yv1 | yv2]
#define MPAD 50048         // 391 * 128
#define EPW 4              // edge-PAIRS per wave per pass (8 edges/wave)

typedef __attribute__((ext_vector_type(8))) __bf16 bf16x8;
typedef __attribute__((ext_vector_type(4))) float f32x4;
typedef unsigned long long u64;

static __device__ __forceinline__ unsigned short f2bf(float f) {
    union { float f; unsigned u; } v; v.f = f;
    unsigned r = v.u + 0x7FFFu + ((v.u >> 16) & 1u);   // RNE
    return (unsigned short)(r >> 16);
}
static __device__ __forceinline__ float bf2f(unsigned short h) {
    union { unsigned u; float f; } v; v.u = ((unsigned)h) << 16;
    return v.f;
}

// ---- phase 0a: x fp32 -> bf16, padded to MPAD rows (pad rows = 0) ----
__global__ void k_cvt_x(const float* __restrict__ x, unsigned short* __restrict__ xb) {
    int i = blockIdx.x * blockDim.x + threadIdx.x;
    if (i >= MPAD * CH / 4) return;
    int base = i << 2;
    unsigned short s0 = 0, s1 = 0, s2 = 0, s3 = 0;
    if (base < NODES * CH) {
        const f32x4 v = *reinterpret_cast<const f32x4*>(x + base);
        s0 = f2bf(v[0]); s1 = f2bf(v[1]); s2 = f2bf(v[2]); s3 = f2bf(v[3]);
    }
    u64 p = (u64)s0 | ((u64)s1 << 16) | ((u64)s2 << 32) | ((u64)s3 << 48);
    *reinterpret_cast<u64*>(xb + base) = p;
}

// ---- phase 0b: Wb[512][128] bf16 (B^T). col n: ym1 | ym2 | yv1 | yv2 ----
__global__ void k_pack_w(const float* __restrict__ wm, const float* __restrict__ wv,
                         unsigned short* __restrict__ wb) {
    int i = blockIdx.x * blockDim.x + threadIdx.x;      // 0..65535
    if (i >= NCOL * CH) return;
    int n = i >> 7, k = i & 127;
    float v;
    if (n < 128)      v = wm[n * 256 + k];               // ym1 = w_mean[:, :128]
    else if (n < 256) v = wm[(n - 128) * 256 + 128 + k]; // ym2 = w_mean[:, 128:]
    else if (n < 384) v = wv[(n - 256) * 256 + k];       // yv1
    else              v = wv[(n - 384) * 256 + 128 + k]; // yv2
    wb[i] = f2bf(v);
}

// ---- phase 1: tab[MPAD][512](bf16) = Xb @ Wb^T (MFMA 16x16x32) ----
__global__ __launch_bounds__(256) void k_gemm(const unsigned short* __restrict__ xb,
                                              const unsigned short* __restrict__ wb,
                                              unsigned short* __restrict__ th) {
    const int lane = threadIdx.x & 63;
    const int wave = threadIdx.x >> 6;
    const int rowbase = blockIdx.x * 128 + (wave >> 1) * 64;
    const int colbase = blockIdx.y * 128 + (wave & 1) * 64;
    const int lr = lane & 15;
    const int kg = lane >> 4;
    f32x4 acc[4][4] = {};
#pragma unroll
    for (int ks = 0; ks < 4; ++ks) {
        const int k = ks * 32 + kg * 8;
        bf16x8 af[4], bfr[4];
#pragma unroll
        for (int a = 0; a < 4; ++a)
            af[a] = *reinterpret_cast<const bf16x8*>(xb + (size_t)(rowbase + a * 16 + lr) * CH + k);
#pragma unroll
        for (int b = 0; b < 4; ++b)
            bfr[b] = *reinterpret_cast<const bf16x8*>(wb + (size_t)(colbase + b * 16 + lr) * CH + k);
#pragma unroll
        for (int a = 0; a < 4; ++a)
#pragma unroll
            for (int b = 0; b < 4; ++b)
                acc[a][b] = __builtin_amdgcn_mfma_f32_16x16x32_bf16(af[a], bfr[b], acc[a][b], 0, 0, 0);
    }
    const int crow = (lane >> 4) * 4;   // C/D: col = lane&15, row = (lane>>4)*4 + reg
    const int ccol = lane & 15;
#pragma unroll
    for (int a = 0; a < 4; ++a)
#pragma unroll
        for (int b = 0; b < 4; ++b)
#pragma unroll
            for (int j = 0; j < 4; ++j) {
                int row = rowbase + a * 16 + crow + j;
                int col = colbase + b * 16 + ccol;
                th[(size_t)row * NCOL + col] = f2bf(acc[a][b][j]);
            }
}

// ---- phase 1b: in-place int8 quantization. One wave per node.
// Lane l reads cols [l*8, l*8+8) (16B bf16); lanes 0-31 = half0 (mean), 32-63 = half1.
// Per-half max via 32-lane shfl reduce; s = max/127; int8 bytes written to the FIRST
// 512 bytes of the same row (read-before-write within the wave => race-free).
// Scales -> sc[(node<<1)|half].
__global__ __launch_bounds__(256) void k_quant(unsigned short* __restrict__ tab,
                                               float* __restrict__ sc) {
    const int node = blockIdx.x * 4 + (threadIdx.x >> 6);    // 12500*4 = 50000 exact
    const int lane = threadIdx.x & 63;
    unsigned short* row = tab + (size_t)node * NCOL;
    const u64 d0 = *reinterpret_cast<const u64*>(row + lane * 8);
    const u64 d1 = *reinterpret_cast<const u64*>(row + lane * 8 + 4);
    float v[8];
#pragma unroll
    for (int k = 0; k < 4; ++k) {
        v[k]     = bf2f((unsigned short)(d0 >> (16 * k)));
        v[k + 4] = bf2f((unsigned short)(d1 >> (16 * k)));
    }
    float m = 0.f;
#pragma unroll
    for (int k = 0; k < 8; ++k) m = fmaxf(m, fabsf(v[k]));
#pragma unroll
    for (int off = 1; off < 32; off <<= 1)                   // reduce within 32-lane half
        m = fmaxf(m, __shfl_xor(m, off, 64));
    const float s   = (m > 1e-20f) ? m * (1.0f / 127.0f) : 1.0f;
    const float inv = (m > 1e-20f) ? 127.0f / m : 0.0f;
    if ((lane & 31) == 0) sc[(node << 1) | (lane >> 5)] = s;
    u64 packed = 0;
#pragma unroll
    for (int k = 0; k < 8; ++k) {
        int q = __float2int_rn(v[k] * inv);
        q = max(-127, min(127, q));
        packed |= (u64)((unsigned)q & 0xFFu) << (8 * k);
    }
    *reinterpret_cast<u64*>(reinterpret_cast<char*>(row) + lane * 8) = packed;
}

// ---- phase 2: per-HALF pass over int8 table. 2 edges per wave iter, EPW iters.
// q-row = first 512 bytes of each 1024B tab row. Per pass pool = 12.8 MB.
template <int HALF>
__global__ __launch_bounds__(256) void k_edges_q(const int* __restrict__ ei,
                                                 const char* __restrict__ q,
                                                 const float* __restrict__ sc,
                                                 float* __restrict__ out) {
    const int wave = threadIdx.x >> 6;
    const int lane = threadIdx.x & 63;
    const int es = lane >> 5;
    const int j = lane & 31;
    const int ebase = (blockIdx.x * 4 + wave) * (2 * EPW);

    int rr[EPW], cc[EPW];
#pragma unroll
    for (int i = 0; i < EPW; ++i) {
        int e = ebase + 2 * i + es;
        rr[i] = ei[e];
        cc[i] = ei[EDGES + e];
    }
    int wa[EPW], wb_[EPW];
    float sa[EPW], sb[EPW];
#pragma unroll
    for (int i = 0; i < EPW; ++i) {
        wa[i]  = *reinterpret_cast<const int*>(q + (size_t)rr[i] * 1024 + HALF * 256 + j * 4);
        wb_[i] = *reinterpret_cast<const int*>(q + (size_t)cc[i] * 1024 + HALF * 256 + 128 + j * 4);
        sa[i] = sc[(rr[i] << 1) | HALF];
        sb[i] = sc[(cc[i] << 1) | HALF];
    }
    const size_t obase = (size_t)HALF * ((size_t)EDGES * 128) + (size_t)j * 4;
#pragma unroll
    for (int i = 0; i < EPW; ++i) {
        const int e = ebase + 2 * i + es;
        f32x4 s;
#pragma unroll
        for (int k = 0; k < 4; ++k) {
            int qa = (wa[i]  << (24 - 8 * k)) >> 24;     // sext byte k
            int qb = (wb_[i] << (24 - 8 * k)) >> 24;
            s[k] = sa[i] * (float)qa + sb[i] * (float)qb;
        }
        __builtin_nontemporal_store(
            s, reinterpret_cast<f32x4*>(out + obase + (size_t)e * 128));
    }
}

// ---- bf16 fallback pass (if ws too small for scales array — shouldn't happen) ----
template <int HALF>
__global__ __launch_bounds__(256) void k_edges_p(const int* __restrict__ ei,
                                                 const unsigned short* __restrict__ th,
                                                 float* __restrict__ out) {
    const int wave = threadIdx.x >> 6;
    const int lane = threadIdx.x & 63;
    const int es = lane >> 5;
    const int j = lane & 31;
    const int ebase = (blockIdx.x * 4 + wave) * (2 * EPW);
    int rr[EPW], cc[EPW];
#pragma unroll
    for (int i = 0; i < EPW; ++i) {
        int e = ebase + 2 * i + es;
        rr[i] = ei[e];
        cc[i] = ei[EDGES + e];
    }
    u64 pa[EPW], pb[EPW];
#pragma unroll
    for (int i = 0; i < EPW; ++i) {
        pa[i] = *reinterpret_cast<const u64*>(th + (size_t)rr[i] * NCOL + HALF * 256 + j * 4);
        pb[i] = *reinterpret_cast<const u64*>(th + (size_t)cc[i] * NCOL + HALF * 256 + 128 + j * 4);
    }
    const size_t obase = (size_t)HALF * ((size_t)EDGES * 128) + (size_t)j * 4;
#pragma unroll
    for (int i = 0; i < EPW; ++i) {
        const int e = ebase + 2 * i + es;
        f32x4 s;
        s[0] = bf2f((unsigned short)pa[i])         + bf2f((unsigned short)pb[i]);
        s[1] = bf2f((unsigned short)(pa[i] >> 16)) + bf2f((unsigned short)(pb[i] >> 16));
        s[2] = bf2f((unsigned short)(pa[i] >> 32)) + bf2f((unsigned short)(pb[i] >> 32));
        s[3] = bf2f((unsigned short)(pa[i] >> 48)) + bf2f((unsigned short)(pb[i] >> 48));
        __builtin_nontemporal_store(
            s, reinterpret_cast<f32x4*>(out + obase + (size_t)e * 128));
    }
}

// ---- last-resort fallback: direct fp32 per-edge GEMV ----
__global__ void k_naive(const float* __restrict__ x, const int* __restrict__ ei,
                        const float* __restrict__ wm, const float* __restrict__ wv,
                        float* __restrict__ out) {
    __shared__ float xs[256];
    int e = blockIdx.x;
    int t = threadIdx.x;
    int r = ei[e], c = ei[EDGES + e];
    xs[t] = (t < 128) ? x[(size_t)r * 128 + t] : x[(size_t)c * 128 + (t - 128)];
    __syncthreads();
    const float* w = (t < 128) ? (wm + (size_t)t * 256) : (wv + (size_t)(t - 128) * 256);
    float acc = 0.f;
#pragma unroll 8
    for (int k = 0; k < 256; ++k) acc = fmaf(xs[k], w[k], acc);
    size_t ooff = (t < 128) ? ((size_t)e * 128 + t)
                            : ((size_t)EDGES * 128 + (size_t)e * 128 + (t - 128));
    out[ooff] = acc;
}

extern "C" void kernel_launch(void* const* d_in, const int* in_sizes, int n_in,
                              void* d_out, int out_size, void* d_ws, size_t ws_size,
                              hipStream_t stream) {
    const float* x  = (const float*)d_in[0];
    const int*   ei = (const int*)d_in[1];
    const float* wm = (const float*)d_in[2];
    const float* wv = (const float*)d_in[3];
    float* out = (float*)d_out;

    const size_t xb_b = (size_t)MPAD * CH * 2;     // 12,812,288
    const size_t wb_b = (size_t)NCOL * CH * 2;     //    131,072
    const size_t th_b = (size_t)MPAD * NCOL * 2;   // 51,249,152
    const size_t sc_b = (size_t)NODES * 2 * 4;     //    400,000

    const size_t need_tab = xb_b + wb_b + th_b;            // 64.2 MB
    const size_t need_q   = need_tab + sc_b;               // 64.6 MB

    if (ws_size < need_tab) {            // correctness insurance only
        k_naive<<<EDGES, 256, 0, stream>>>(x, ei, wm, wv, out);
        return;
    }

    unsigned short* xb  = (unsigned short*)d_ws;
    unsigned short* wb  = (unsigned short*)((char*)d_ws + xb_b);
    unsigned short* tab = (unsigned short*)((char*)d_ws + xb_b + wb_b);
    float*          sc  = (float*)((char*)d_ws + need_tab);

    k_cvt_x<<<(MPAD * CH / 4 + 255) / 256, 256, 0, stream>>>(x, xb);
    k_pack_w<<<(NCOL * CH + 255) / 256, 256, 0, stream>>>(wm, wv, wb);
    dim3 g(MPAD / 128, NCOL / 128);
    k_gemm<<<g, 256, 0, stream>>>(xb, wb, tab);

    const int eb = EDGES / (4 * 2 * EPW);          // 25000 blocks per pass
    if (ws_size >= need_q) {
        k_quant<<<NODES / 4, 256, 0, stream>>>(tab, sc);          // 12500 blocks
        k_edges_q<0><<<eb, 256, 0, stream>>>(ei, (const char*)tab, sc, out);
        k_edges_q<1><<<eb, 256, 0, stream>>>(ei, (const char*)tab, sc, out);
    } else {
        k_edges_p<0><<<eb, 256, 0, stream>>>(ei, tab, out);
        k_edges_p<1><<<eb, 256, 0, stream>>>(ei, tab, out);
    }
}

// Round 13
// 226.471 us; speedup vs baseline: 1.5361x; 1.0015x over previous
//
#include <hip/hip_runtime.h>
#include <hip/hip_bf16.h>

#define NODES 50000
#define EDGES 800000
#define CH 128
#define NCOL 512           // table cols per node: [ym1 | ym2 | yv1 | yv2]
#define MPAD 50048         // 782 * 64
#define QROWS 64           // node-rows per k_gemmq block
#define EPW 4              // edge-PAIRS per wave (8 edges/wave)

typedef __attribute__((ext_vector_type(8))) __bf16 bf16x8;
typedef __attribute__((ext_vector_type(4))) float f32x4;
typedef __attribute__((ext_vector_type(2))) float f32x2;
typedef unsigned long long u64;

static __device__ __forceinline__ unsigned short f2bf(float f) {
    union { float f; unsigned u; } v; v.f = f;
    unsigned r = v.u + 0x7FFFu + ((v.u >> 16) & 1u);   // RNE
    return (unsigned short)(r >> 16);
}

// ---- phase 0a: x fp32 -> bf16, padded to MPAD rows (pad rows = 0) ----
__global__ void k_cvt_x(const float* __restrict__ x, unsigned short* __restrict__ xb) {
    int i = blockIdx.x * blockDim.x + threadIdx.x;
    if (i >= MPAD * CH / 4) return;
    int base = i << 2;
    unsigned short s0 = 0, s1 = 0, s2 = 0, s3 = 0;
    if (base < NODES * CH) {
        const f32x4 v = *reinterpret_cast<const f32x4*>(x + base);
        s0 = f2bf(v[0]); s1 = f2bf(v[1]); s2 = f2bf(v[2]); s3 = f2bf(v[3]);
    }
    u64 p = (u64)s0 | ((u64)s1 << 16) | ((u64)s2 << 32) | ((u64)s3 << 48);
    *reinterpret_cast<u64*>(xb + base) = p;
}

// ---- phase 0b: Wb[512][128] bf16 (B^T). phys col n: ym1 | ym2 | yv1 | yv2 ----
__global__ void k_pack_w(const float* __restrict__ wm, const float* __restrict__ wv,
                         unsigned short* __restrict__ wb) {
    int i = blockIdx.x * blockDim.x + threadIdx.x;      // 0..65535
    if (i >= NCOL * CH) return;
    int n = i >> 7, k = i & 127;
    float v;
    if (n < 128)      v = wm[n * 256 + k];               // ym1 = w_mean[:, :128]
    else if (n < 256) v = wm[(n - 128) * 256 + 128 + k]; // ym2 = w_mean[:, 128:]
    else if (n < 384) v = wv[(n - 256) * 256 + k];       // yv1
    else              v = wv[(n - 384) * 256 + 128 + k]; // yv2
    wb[i] = f2bf(v);
}

// ---- phase 1 (fused GEMM + int8 quant): per block 64 node-rows x 512 cols.
// Wave w covers phys cols [128w, 128w+128). B-perm: frag b, lane lr reads
// wb phys col (128w + 8*lr + b)  =>  lane ccol's acc[a][b][j] holds
// row (rowbase+16a+crow+j), phys col (128w + 8*ccol + b): 8 consecutive cols
// per lane => u64 pack, no byte scatter. Per-(row,half) max: shfl width-16
// reduce (16 lanes share 16 rows) + LDS cross-wave combine (half = wave>>1).
__global__ __launch_bounds__(256) void k_gemmq(const unsigned short* __restrict__ xb,
                                               const unsigned short* __restrict__ wb,
                                               char* __restrict__ qt,
                                               float* __restrict__ sc) {
    __shared__ float sM[2][2][QROWS];                       // [half][wave&1][row]
    __shared__ __align__(16) char sQ[QROWS][NCOL];          // 32 KB int8 tile
    const int lane = threadIdx.x & 63;
    const int wave = threadIdx.x >> 6;                      // 0..3
    const int rowbase = blockIdx.x * QROWS;
    const int lr = lane & 15;
    const int kg = lane >> 4;

    f32x4 acc[4][8] = {};
#pragma unroll
    for (int ks = 0; ks < 4; ++ks) {
        const int k = ks * 32 + kg * 8;
        bf16x8 af[4], bfr[8];
#pragma unroll
        for (int a = 0; a < 4; ++a)
            af[a] = *reinterpret_cast<const bf16x8*>(xb + (size_t)(rowbase + a * 16 + lr) * CH + k);
#pragma unroll
        for (int b = 0; b < 8; ++b)
            bfr[b] = *reinterpret_cast<const bf16x8*>(wb + (size_t)(wave * 128 + lr * 8 + b) * CH + k);
#pragma unroll
        for (int a = 0; a < 4; ++a)
#pragma unroll
            for (int b = 0; b < 8; ++b)
                acc[a][b] = __builtin_amdgcn_mfma_f32_16x16x32_bf16(af[a], bfr[b], acc[a][b], 0, 0, 0);
    }

    const int crow = (lane >> 4) * 4;
    const int ccol = lane & 15;
    const int half = wave >> 1;

    // per-lane row max over its 8 cols, then over the 16-lane subgroup (same rows)
    float m[4][4];
#pragma unroll
    for (int a = 0; a < 4; ++a)
#pragma unroll
        for (int j = 0; j < 4; ++j) {
            float mm = 0.f;
#pragma unroll
            for (int b = 0; b < 8; ++b) mm = fmaxf(mm, fabsf(acc[a][b][j]));
            m[a][j] = mm;
        }
#pragma unroll
    for (int off = 1; off < 16; off <<= 1)
#pragma unroll
        for (int a = 0; a < 4; ++a)
#pragma unroll
            for (int j = 0; j < 4; ++j)
                m[a][j] = fmaxf(m[a][j], __shfl_xor(m[a][j], off, 16));
    if (ccol == 0)
#pragma unroll
        for (int a = 0; a < 4; ++a)
#pragma unroll
            for (int j = 0; j < 4; ++j)
                sM[half][wave & 1][a * 16 + crow + j] = m[a][j];
    __syncthreads();

    // combined max -> quantize -> pack u64 -> LDS
#pragma unroll
    for (int a = 0; a < 4; ++a)
#pragma unroll
        for (int j = 0; j < 4; ++j) {
            const int row = a * 16 + crow + j;
            const float rm = fmaxf(sM[half][0][row], sM[half][1][row]);
            const float inv = (rm > 1e-20f) ? 127.0f / rm : 0.0f;
            u64 pk = 0;
#pragma unroll
            for (int b = 0; b < 8; ++b) {
                int q = __float2int_rn(acc[a][b][j] * inv);
                q = max(-127, min(127, q));
                pk |= (u64)((unsigned)q & 0xFFu) << (8 * b);
            }
            *reinterpret_cast<u64*>(&sQ[row][wave * 128 + ccol * 8]) = pk;
        }
    // scales: 128 threads cover (half, row)
    if (threadIdx.x < 2 * QROWS) {
        const int h = threadIdx.x >> 6, row = threadIdx.x & 63;
        const float rm = fmaxf(sM[h][0][row], sM[h][1][row]);
        sc[(size_t)(rowbase + row) * 2 + h] = (rm > 1e-20f) ? rm * (1.0f / 127.0f) : 1.0f;
    }
    __syncthreads();

    // copy out 32 KB linear
#pragma unroll
    for (int t = 0; t < 8; ++t) {
        const int off = t * 4096 + threadIdx.x * 16;
        f32x4 v = *reinterpret_cast<const f32x4*>(&sQ[0][0] + off);
        *reinterpret_cast<f32x4*>(qt + (size_t)rowbase * NCOL + off) = v;
    }
}

// ---- phase 2: single merged pass over int8 table (both halves per edge) ----
__global__ __launch_bounds__(256) void k_edges_m(const int* __restrict__ ei,
                                                 const char* __restrict__ qt,
                                                 const float* __restrict__ sc,
                                                 float* __restrict__ out) {
    const int wave = threadIdx.x >> 6;
    const int lane = threadIdx.x & 63;
    const int es = lane >> 5;
    const int j = lane & 31;
    const int ebase = (blockIdx.x * 4 + wave) * (2 * EPW);

    int rr[EPW], cc[EPW];
#pragma unroll
    for (int i = 0; i < EPW; ++i) {
        int e = ebase + 2 * i + es;
        rr[i] = ei[e];
        cc[i] = ei[EDGES + e];
    }
    int am[EPW], av[EPW], bm[EPW], bv[EPW];
    f32x2 sr[EPW], scl[EPW];
#pragma unroll
    for (int i = 0; i < EPW; ++i) {
        const char* qr = qt + (size_t)rr[i] * NCOL;
        const char* qc = qt + (size_t)cc[i] * NCOL;
        am[i] = *reinterpret_cast<const int*>(qr + j * 4);           // ym1[r]
        av[i] = *reinterpret_cast<const int*>(qr + 256 + j * 4);     // yv1[r]
        bm[i] = *reinterpret_cast<const int*>(qc + 128 + j * 4);     // ym2[c]
        bv[i] = *reinterpret_cast<const int*>(qc + 384 + j * 4);     // yv2[c]
        sr[i]  = *reinterpret_cast<const f32x2*>(sc + (size_t)rr[i] * 2);
        scl[i] = *reinterpret_cast<const f32x2*>(sc + (size_t)cc[i] * 2);
    }
#pragma unroll
    for (int i = 0; i < EPW; ++i) {
        const int e = ebase + 2 * i + es;
        f32x4 sm_, sv_;
#pragma unroll
        for (int k = 0; k < 4; ++k) {
            const int sh = 24 - 8 * k;
            sm_[k] = sr[i][0] * (float)((am[i] << sh) >> 24)
                   + scl[i][0] * (float)((bm[i] << sh) >> 24);
            sv_[k] = sr[i][1] * (float)((av[i] << sh) >> 24)
                   + scl[i][1] * (float)((bv[i] << sh) >> 24);
        }
        __builtin_nontemporal_store(sm_,
            reinterpret_cast<f32x4*>(out + (size_t)e * 128 + j * 4));
        __builtin_nontemporal_store(sv_,
            reinterpret_cast<f32x4*>(out + (size_t)EDGES * 128 + (size_t)e * 128 + j * 4));
    }
}

// ---- last-resort fallback: direct fp32 per-edge GEMV ----
__global__ void k_naive(const float* __restrict__ x, const int* __restrict__ ei,
                        const float* __restrict__ wm, const float* __restrict__ wv,
                        float* __restrict__ out) {
    __shared__ float xs[256];
    int e = blockIdx.x;
    int t = threadIdx.x;
    int r = ei[e], c = ei[EDGES + e];
    xs[t] = (t < 128) ? x[(size_t)r * 128 + t] : x[(size_t)c * 128 + (t - 128)];
    __syncthreads();
    const float* w = (t < 128) ? (wm + (size_t)t * 256) : (wv + (size_t)(t - 128) * 256);
    float acc = 0.f;
#pragma unroll 8
    for (int k = 0; k < 256; ++k) acc = fmaf(xs[k], w[k], acc);
    size_t ooff = (t < 128) ? ((size_t)e * 128 + t)
                            : ((size_t)EDGES * 128 + (size_t)e * 128 + (t - 128));
    out[ooff] = acc;
}

extern "C" void kernel_launch(void* const* d_in, const int* in_sizes, int n_in,
                              void* d_out, int out_size, void* d_ws, size_t ws_size,
                              hipStream_t stream) {
    const float* x  = (const float*)d_in[0];
    const int*   ei = (const int*)d_in[1];
    const float* wm = (const float*)d_in[2];
    const float* wv = (const float*)d_in[3];
    float* out = (float*)d_out;

    const size_t xb_b = (size_t)MPAD * CH * 2;      // 12,812,288
    const size_t wb_b = (size_t)NCOL * CH * 2;      //    131,072
    const size_t qt_b = (size_t)MPAD * NCOL;        // 25,624,576
    const size_t sc_b = (size_t)MPAD * 2 * 4;       //    400,384

    if (ws_size < xb_b + wb_b + qt_b + sc_b) {      // correctness insurance only
        k_naive<<<EDGES, 256, 0, stream>>>(x, ei, wm, wv, out);
        return;
    }

    unsigned short* xb = (unsigned short*)d_ws;
    unsigned short* wb = (unsigned short*)((char*)d_ws + xb_b);
    char*           qt = (char*)d_ws + xb_b + wb_b;
    float*          sc = (float*)((char*)d_ws + xb_b + wb_b + qt_b);

    k_cvt_x<<<(MPAD * CH / 4 + 255) / 256, 256, 0, stream>>>(x, xb);
    k_pack_w<<<(NCOL * CH + 255) / 256, 256, 0, stream>>>(wm, wv, wb);
    k_gemmq<<<MPAD / QROWS, 256, 0, stream>>>(xb, wb, qt, sc);      // 782 blocks
    k_edges_m<<<EDGES / (4 * 2 * EPW), 256, 0, stream>>>(ei, qt, sc, out);  // 25000
}